// Round 1
// baseline (63.007 us; speedup 1.0000x reference)
//
#include <hip/hip_runtime.h>
#include <hip/hip_bf16.h>
#include <stdint.h>

typedef __attribute__((ext_vector_type(8)))  __bf16   bf16x8;
typedef __attribute__((ext_vector_type(16))) float    f32x16;
typedef __attribute__((ext_vector_type(4)))  uint32_t u32x4;
typedef __attribute__((ext_vector_type(4)))  float    f32x4;

#define NB   32      // batch
#define NN   2000    // seq len
#define NK   32      // neighbors
#define NF   64      // features
#define NOUT 128     // outputs
#define NSTEP 130    // packed K (2048 x-part + 32 dist) / 16

// ---------------------------------------------------------------------------
// Prep 1: x (B,N,F) f32 -> xb2[n][4KB swizzled bf16 [32 b][64 f]]
//         also distances -> db[n][32] bf16
// Swizzle: byte_in_tile = (b*128 + f*2) ^ ((b&7)<<4)  (G4 verified pattern)
// ---------------------------------------------------------------------------
__global__ void kprep_x(const float* __restrict__ x, const float* __restrict__ dist,
                        __bf16* __restrict__ xb2, __bf16* __restrict__ db) {
  const int n = blockIdx.x;
  const int t = threadIdx.x;
  const int bb = t >> 3;          // batch 0..31
  const int f0 = (t & 7) << 3;    // feature start 0..56
  const float* src = x + ((size_t)bb * NN + n) * NF + f0;
  f32x4 v0 = *(const f32x4*)(src);
  f32x4 v1 = *(const f32x4*)(src + 4);
  bf16x8 r;
  r[0] = (__bf16)v0[0]; r[1] = (__bf16)v0[1]; r[2] = (__bf16)v0[2]; r[3] = (__bf16)v0[3];
  r[4] = (__bf16)v1[0]; r[5] = (__bf16)v1[1]; r[6] = (__bf16)v1[2]; r[7] = (__bf16)v1[3];
  const int off = ((bb * 128) + (f0 << 1)) ^ ((bb & 7) << 4);
  *(bf16x8*)((char*)xb2 + ((size_t)n << 12) + off) = r;
  if (t < NK) db[n * NK + t] = (__bf16)dist[n * NK + t];
}

// ---------------------------------------------------------------------------
// Prep 2: W (128, 2080) f32 -> Wf bf16 in B-fragment order.
// Packed column kg: kg<2048 -> orig col (kg>>6)*65 + (kg&63)   (x part)
//                   kg>=2048 -> orig col (kg-2048)*65 + 64     (distance part)
// Fragment layout: Wf[(kstep*4 + wave)*64 + lane][j], o = wave*32+(lane&31),
//                  k = kstep*16 + (lane>>5)*8 + j
// ---------------------------------------------------------------------------
__global__ void kprep_w(const float* __restrict__ W, __bf16* __restrict__ Wf) {
  const int kstep = blockIdx.x;
  const int t = threadIdx.x;
  const int lane = t & 63;
  const int wv = t >> 6;
  const int o = wv * 32 + (lane & 31);
  const int kbase = kstep * 16 + (lane >> 5) * 8;
  bf16x8 r;
#pragma unroll
  for (int j = 0; j < 8; ++j) {
    const int kg = kbase + j;
    const int col = (kg < 2048) ? ((kg >> 6) * 65 + (kg & 63)) : ((kg - 2048) * 65 + 64);
    r[j] = (__bf16)W[(size_t)o * 2080 + col];
  }
  *(bf16x8*)(Wf + (((size_t)kstep * 256 + t) << 3)) = r;
}

// ---------------------------------------------------------------------------
// Main: 1 block = 2 seq positions (n0, n0+1), 4 waves = 4 output-col groups.
// Per wave: D[32 batch][32 out] via mfma_f32_32x32x16_bf16, K' = 2080.
// ---------------------------------------------------------------------------
__global__ __launch_bounds__(256, 4) void kmain(
    const int* __restrict__ nbrs, const float* __restrict__ bias,
    const __bf16* __restrict__ xb2, const __bf16* __restrict__ Wf,
    const __bf16* __restrict__ db, float* __restrict__ out) {
  __shared__ u32x4 lds[2][4][256];   // [n-of-2][nbr-in-chunk][4KB swizzled tile]

  const int n0   = blockIdx.x * 2;
  const int t    = threadIdx.x;
  const int lane = t & 63;
  const int w    = t >> 6;
  const int col  = lane & 31;   // A-row (batch) and B-col (out) lane index
  const int half = lane >> 5;
  const int swz  = col & 7;

  f32x16 acc0 = {};
  f32x16 acc1 = {};

  // per-lane base of B-fragment stream; stride per k-step = 4*64*8 elems
  const __bf16* wfp = Wf + (((size_t)w * 64 + lane) << 3);

  for (int chunk = 0; chunk < 8; ++chunk) {
    // ---- stage 8 x 4KB neighbor tiles (2 n's x 4 neighbors) via registers
    u32x4 stg[8];
#pragma unroll
    for (int gg = 0; gg < 2; ++gg) {
#pragma unroll
      for (int c = 0; c < 4; ++c) {
        const int nb = nbrs[(n0 + gg) * NK + chunk * 4 + c];
        stg[gg * 4 + c] = *(const u32x4*)((const char*)xb2 + ((size_t)nb << 12) + t * 16);
      }
    }
    __syncthreads();             // previous chunk's compute done
#pragma unroll
    for (int i = 0; i < 8; ++i) lds[i >> 2][i & 3][t] = stg[i];
    __syncthreads();             // tiles visible

    // ---- compute: 4 neighbors x 4 k-steps x (2 n's)
#pragma unroll
    for (int c = 0; c < 4; ++c) {
      const int sg = (chunk * 4 + c) * 4;
#pragma unroll
      for (int s = 0; s < 4; ++s) {
        bf16x8 bfr = *(const bf16x8*)(wfp + ((size_t)(sg + s) << 11));
        // A-frag: row=col(batch), f bytes = s*32 + half*16, XOR-swizzled
        const int aoff = col * 8 + ((s * 2 + half) ^ swz);   // in u32x4 units
        bf16x8 a0 = *(const bf16x8*)&lds[0][c][aoff];
        bf16x8 a1 = *(const bf16x8*)&lds[1][c][aoff];
        acc0 = __builtin_amdgcn_mfma_f32_32x32x16_bf16(a0, bfr, acc0, 0, 0, 0);
        acc1 = __builtin_amdgcn_mfma_f32_32x32x16_bf16(a1, bfr, acc1, 0, 0, 0);
      }
    }
  }

  // ---- distance part: packed k-steps 128,129; A rows all equal d[n][kk]
#pragma unroll
  for (int s = 0; s < 2; ++s) {
    bf16x8 bfr = *(const bf16x8*)(wfp + ((size_t)(128 + s) << 11));
    bf16x8 dv0 = *(const bf16x8*)((const char*)db + (size_t)n0 * 64 + s * 32 + half * 16);
    bf16x8 dv1 = *(const bf16x8*)((const char*)db + ((size_t)n0 + 1) * 64 + s * 32 + half * 16);
    acc0 = __builtin_amdgcn_mfma_f32_32x32x16_bf16(dv0, bfr, acc0, 0, 0, 0);
    acc1 = __builtin_amdgcn_mfma_f32_32x32x16_bf16(dv1, bfr, acc1, 0, 0, 0);
  }

  // ---- epilogue: D col = lane&31 -> out o, row = (r&3)+8*(r>>2)+4*half -> batch
  const int o = w * 32 + col;
  const float bv = bias[o];
#pragma unroll
  for (int r = 0; r < 16; ++r) {
    const int row = (r & 3) + 8 * (r >> 2) + 4 * half;
    out[((size_t)row * NN + n0) * NOUT + o]     = acc0[r] + bv;
    out[((size_t)row * NN + n0 + 1) * NOUT + o] = acc1[r] + bv;
  }
}

// ---------------------------------------------------------------------------
extern "C" void kernel_launch(void* const* d_in, const int* in_sizes, int n_in,
                              void* d_out, int out_size, void* d_ws, size_t ws_size,
                              hipStream_t stream) {
  const float* x    = (const float*)d_in[0];
  const int*   nbrs = (const int*)d_in[1];     // JAX x64-off => int32
  const float* dist = (const float*)d_in[2];
  const float* W    = (const float*)d_in[3];
  const float* bias = (const float*)d_in[4];
  float* out = (float*)d_out;

  char* ws = (char*)d_ws;
  __bf16* xb2 = (__bf16*)(ws);                          // 2000*4096      = 8,192,000 B
  __bf16* Wf  = (__bf16*)(ws + 8192000);                // 130*256*8*2    =   532,480 B
  __bf16* db  = (__bf16*)(ws + 8192000 + 532480);       // 2000*32*2      =   128,000 B

  kprep_x<<<NN, 256, 0, stream>>>(x, dist, xb2, db);
  kprep_w<<<NSTEP, 256, 0, stream>>>(W, Wf);
  kmain<<<NN / 2, 256, 0, stream>>>(nbrs, bias, xb2, Wf, db, out);
}

// Round 2
// 62.808 us; speedup vs baseline: 1.0032x; 1.0032x over previous
//
#include <hip/hip_runtime.h>
#include <hip/hip_bf16.h>
#include <stdint.h>

typedef __attribute__((ext_vector_type(8)))  __bf16   bf16x8;
typedef __attribute__((ext_vector_type(16))) float    f32x16;
typedef __attribute__((ext_vector_type(4)))  float    f32x4;

#define NB   32
#define NN   2000
#define NK   32
#define NF   64
#define NOUT 128
#define NSTEP 130   // packed K: 2048 x-part + 32 dist, /16

#define GLOBAL_AS __attribute__((address_space(1)))
#define LDS_AS    __attribute__((address_space(3)))

// ---------------------------------------------------------------------------
// Prep 1: x (B,N,F) f32 -> xb2[n] 4KB tile in MFMA A-fragment order:
//   byte_off(s, half, col, j) = s*1024 + half*512 + col*16 + j*2
//   holds x[batch=col][f = s*16 + half*8 + j]  (lane l = half*32+col reads l*16)
// Also distances -> db[n][32] bf16.
// ---------------------------------------------------------------------------
__global__ void kprep_x(const float* __restrict__ x, const float* __restrict__ dist,
                        __bf16* __restrict__ xb2, __bf16* __restrict__ db) {
  const int n = blockIdx.x;
  const int t = threadIdx.x;
  const int bb = t >> 3;          // batch / col 0..31
  const int f0 = (t & 7) << 3;    // feature start 0..56
  const float* src = x + ((size_t)bb * NN + n) * NF + f0;
  f32x4 v0 = *(const f32x4*)(src);
  f32x4 v1 = *(const f32x4*)(src + 4);
  bf16x8 r;
  r[0] = (__bf16)v0[0]; r[1] = (__bf16)v0[1]; r[2] = (__bf16)v0[2]; r[3] = (__bf16)v0[3];
  r[4] = (__bf16)v1[0]; r[5] = (__bf16)v1[1]; r[6] = (__bf16)v1[2]; r[7] = (__bf16)v1[3];
  const int off = ((f0 >> 4) << 10) + (((f0 >> 3) & 1) << 9) + (bb << 4); // bytes
  *(bf16x8*)((char*)xb2 + ((size_t)n << 12) + off) = r;
  if (t < NK) db[n * NK + t] = (__bf16)dist[n * NK + t];
}

// ---------------------------------------------------------------------------
// Prep 2: W (128, 2080) f32 -> Wf bf16 in B-fragment order (unchanged, verified).
// ---------------------------------------------------------------------------
__global__ void kprep_w(const float* __restrict__ W, __bf16* __restrict__ Wf) {
  const int kstep = blockIdx.x;
  const int t = threadIdx.x;
  const int lane = t & 63;
  const int wv = t >> 6;
  const int o = wv * 32 + (lane & 31);
  const int kbase = kstep * 16 + (lane >> 5) * 8;
  bf16x8 r;
#pragma unroll
  for (int j = 0; j < 8; ++j) {
    const int kg = kbase + j;
    const int col = (kg < 2048) ? ((kg >> 6) * 65 + (kg & 63)) : ((kg - 2048) * 65 + 64);
    r[j] = (__bf16)W[(size_t)o * 2080 + col];
  }
  *(bf16x8*)(Wf + (((size_t)kstep * 256 + t) << 3)) = r;
}

// ---------------------------------------------------------------------------
// Main: block = 2 seq positions, 4 waves = 4 out-col groups (32 each).
// Double-buffered LDS (2 x 16KB = 2n x 2nbr x 4KB tiles), global_load_lds
// staging, counted vmcnt(4), 16 chunks of 2 neighbors.
// ---------------------------------------------------------------------------
__global__ __launch_bounds__(256, 4) void kmain(
    const int* __restrict__ nbrs, const float* __restrict__ bias,
    const __bf16* __restrict__ xb2, const __bf16* __restrict__ Wf,
    const __bf16* __restrict__ db, float* __restrict__ out) {
  __shared__ __align__(16) char lds[2][16384];   // [buf][tile(g*2+c)][4KB]

  const int n0   = blockIdx.x * 2;
  const int t    = threadIdx.x;
  const int lane = t & 63;
  const int w    = t >> 6;
  const int col  = lane & 31;
  const int half = lane >> 5;
  const int g    = w >> 1;        // which n this wave stages
  const int c    = w & 1;         // which neighbor-slot this wave stages

  f32x16 acc0 = {};
  f32x16 acc1 = {};

  // Pre-load this wave's 16 neighbor indices (chunk k in lane k).
  int myidx = 0;
  if (lane < 16) myidx = nbrs[(n0 + g) * NK + lane * 2 + c];

  const __bf16* wfp = Wf + (((size_t)(w * 64 + lane)) << 3);

  // stage: wave w copies its 4KB tile of `chunk` into lds[buf] (linear, frag order)
  auto stage = [&](int buf, int chunk) {
    const int nb = __builtin_amdgcn_readlane(myidx, chunk);
    const char* gsrc = (const char*)xb2 + ((size_t)nb << 12) + lane * 16;
    char* ldst = &lds[buf][w << 12];
#pragma unroll
    for (int q = 0; q < 4; ++q) {
      __builtin_amdgcn_global_load_lds(
          (const GLOBAL_AS uint32_t*)(gsrc + (q << 10)),
          (LDS_AS uint32_t*)(ldst + (q << 10)), 16, 0, 0);
    }
  };

  auto compute = [&](int buf, int chunk) {
#pragma unroll
    for (int cc = 0; cc < 2; ++cc) {
#pragma unroll
      for (int s = 0; s < 4; ++s) {
        const int kstep = (chunk * 2 + cc) * 4 + s;
        bf16x8 bfr = *(const bf16x8*)(wfp + ((size_t)kstep << 11));
        bf16x8 a0 = *(const bf16x8*)&lds[buf][((0 * 2 + cc) << 12) + (s << 10) + lane * 16];
        bf16x8 a1 = *(const bf16x8*)&lds[buf][((1 * 2 + cc) << 12) + (s << 10) + lane * 16];
        acc0 = __builtin_amdgcn_mfma_f32_32x32x16_bf16(a0, bfr, acc0, 0, 0, 0);
        acc1 = __builtin_amdgcn_mfma_f32_32x32x16_bf16(a1, bfr, acc1, 0, 0, 0);
      }
    }
  };

  stage(0, 0);
  int cur = 0;
  for (int chunk = 0; chunk < 15; ++chunk) {
    stage(cur ^ 1, chunk + 1);                       // next chunk's gathers in flight
    asm volatile("s_waitcnt vmcnt(4)" ::: "memory"); // current chunk's 4 drained
    __builtin_amdgcn_s_barrier();
    compute(cur, chunk);
    asm volatile("s_waitcnt lgkmcnt(0)" ::: "memory");
    __builtin_amdgcn_s_barrier();                    // buf free for re-stage
    cur ^= 1;
  }
  asm volatile("s_waitcnt vmcnt(0)" ::: "memory");
  __builtin_amdgcn_s_barrier();
  compute(cur, 15);

  // ---- distance part: packed k-steps 128,129; A rows all equal d[n][k]
#pragma unroll
  for (int s = 0; s < 2; ++s) {
    bf16x8 bfr = *(const bf16x8*)(wfp + ((size_t)(128 + s) << 11));
    bf16x8 dv0 = *(const bf16x8*)((const char*)db + (size_t)n0 * 64 + s * 32 + half * 16);
    bf16x8 dv1 = *(const bf16x8*)((const char*)db + ((size_t)n0 + 1) * 64 + s * 32 + half * 16);
    acc0 = __builtin_amdgcn_mfma_f32_32x32x16_bf16(dv0, bfr, acc0, 0, 0, 0);
    acc1 = __builtin_amdgcn_mfma_f32_32x32x16_bf16(dv1, bfr, acc1, 0, 0, 0);
  }

  // ---- epilogue: D col = lane&31 -> out o, row = (r&3)+8*(r>>2)+4*half -> batch
  const int o = w * 32 + col;
  const float bv = bias[o];
#pragma unroll
  for (int r = 0; r < 16; ++r) {
    const int row = (r & 3) + 8 * (r >> 2) + 4 * half;
    out[((size_t)row * NN + n0) * NOUT + o]     = acc0[r] + bv;
    out[((size_t)row * NN + n0 + 1) * NOUT + o] = acc1[r] + bv;
  }
}

// ---------------------------------------------------------------------------
extern "C" void kernel_launch(void* const* d_in, const int* in_sizes, int n_in,
                              void* d_out, int out_size, void* d_ws, size_t ws_size,
                              hipStream_t stream) {
  const float* x    = (const float*)d_in[0];
  const int*   nbrs = (const int*)d_in[1];
  const float* dist = (const float*)d_in[2];
  const float* W    = (const float*)d_in[3];
  const float* bias = (const float*)d_in[4];
  float* out = (float*)d_out;

  char* ws = (char*)d_ws;
  __bf16* xb2 = (__bf16*)(ws);                          // 2000*4096    = 8,192,000 B
  __bf16* Wf  = (__bf16*)(ws + 8192000);                // 130*256*16   =   532,480 B
  __bf16* db  = (__bf16*)(ws + 8192000 + 532480);       // 2000*32*2    =   128,000 B

  kprep_x<<<NN, 256, 0, stream>>>(x, dist, xb2, db);
  kprep_w<<<NSTEP, 256, 0, stream>>>(W, Wf);
  kmain<<<NN / 2, 256, 0, stream>>>(nbrs, bias, xb2, Wf, db, out);
}

// Round 3
// 55.253 us; speedup vs baseline: 1.1403x; 1.1367x over previous
//
#include <hip/hip_runtime.h>
#include <hip/hip_bf16.h>
#include <stdint.h>

typedef __attribute__((ext_vector_type(8)))  __bf16   bf16x8;
typedef __attribute__((ext_vector_type(16))) float    f32x16;
typedef __attribute__((ext_vector_type(8)))  float    f32x8;

#define NB   32
#define NN   2000
#define NK   32
#define NF   64
#define NOUT 128
#define NSTEP 130   // packed K: 2048 x-part + 32 dist, /16

#define GLOBAL_AS __attribute__((address_space(1)))
#define LDS_AS    __attribute__((address_space(3)))

// ---------------------------------------------------------------------------
// Fused prep. Blocks [0,NN): x -> xb2 frag-order tiles (+ dist -> db bf16).
//             Blocks [NN, NN+NSTEP): W -> Wf B-fragment order.
// xb2 tile byte t*16 holds x[batch=col][f=s*16+half*8+j], t=s*64+half*32+col.
// ---------------------------------------------------------------------------
__global__ void kprep(const float* __restrict__ x, const float* __restrict__ dist,
                      const float* __restrict__ W,
                      __bf16* __restrict__ xb2, __bf16* __restrict__ db,
                      __bf16* __restrict__ Wf) {
  const int t = threadIdx.x;
  if (blockIdx.x < NN) {
    const int n = blockIdx.x;
    const int col = t & 31, half = (t >> 5) & 1, s = t >> 6;
    const float* src = x + ((size_t)col * NN + n) * NF + s * 16 + half * 8;
    f32x8 v = *(const f32x8*)src;                     // 32B, aligned
    bf16x8 r;
#pragma unroll
    for (int j = 0; j < 8; ++j) r[j] = (__bf16)v[j];
    *(bf16x8*)((char*)xb2 + ((size_t)n << 12) + t * 16) = r;   // coalesced
    if (t < NK) db[n * NK + t] = (__bf16)dist[n * NK + t];
  } else {
    const int kstep = blockIdx.x - NN;                // 0..129
    const int lane = t & 63;
    const int wv = t >> 6;
    const int o = wv * 32 + (lane & 31);
    const int kbase = kstep * 16 + (lane >> 5) * 8;
    bf16x8 r;
#pragma unroll
    for (int j = 0; j < 8; ++j) {
      const int kg = kbase + j;
      const int c = (kg < 2048) ? ((kg >> 6) * 65 + (kg & 63)) : ((kg - 2048) * 65 + 64);
      r[j] = (__bf16)W[(size_t)o * 2080 + c];
    }
    *(bf16x8*)(Wf + (((size_t)kstep * 256 + t) << 3)) = r;
  }
}

// ---------------------------------------------------------------------------
// Main: block = 4 seq positions, 4 waves = 4 out-col groups (32 each).
// 4 LDS buffers x (4 n x 4KB tile) = 64KB, gather prefetch depth 3,
// B-fragments register-prefetched one chunk ahead, counted vmcnt(8).
// 32 chunks (one neighbor slot each), 16 MFMA / chunk / wave.
// ---------------------------------------------------------------------------
__global__ __launch_bounds__(256, 2) void kmain(
    const int* __restrict__ nbrs, const float* __restrict__ bias,
    const __bf16* __restrict__ xb2, const __bf16* __restrict__ Wf,
    const __bf16* __restrict__ db, float* __restrict__ out) {
  __shared__ __align__(16) char lds[4][4][4096];   // [buf][n'][frag-order tile]

  const int n0   = blockIdx.x * 4;
  const int t    = threadIdx.x;
  const int lane = t & 63;
  const int w    = t >> 6;
  const int col  = lane & 31;
  const int half = lane >> 5;

  f32x16 acc0 = {}, acc1 = {}, acc2 = {}, acc3 = {};

  // lane c (c<32) holds this wave's n (= n0+w) neighbor index for slot c
  int myidx = 0;
  if (lane < NK) myidx = nbrs[(n0 + w) * NK + lane];

  const __bf16* wfp = Wf + (((size_t)(w * 64 + lane)) << 3);

  auto stage = [&](int buf, int c) {         // wave w stages tile of n0+w, nbr c
    const int nb = __builtin_amdgcn_readlane(myidx, c);
    const char* g = (const char*)xb2 + ((size_t)nb << 12) + lane * 16;
    char* l = &lds[buf][w][0];               // wave-uniform LDS base
#pragma unroll
    for (int q = 0; q < 4; ++q)
      __builtin_amdgcn_global_load_lds(
          (const GLOBAL_AS uint32_t*)(g + (q << 10)),
          (LDS_AS uint32_t*)(l + (q << 10)), 16, 0, 0);
  };

  auto loadB = [&](bf16x8* B, int i) {       // 4 B-frags for chunk i
#pragma unroll
    for (int s = 0; s < 4; ++s)
      B[s] = *(const bf16x8*)(wfp + ((size_t)(i * 4 + s) << 11));
  };

  auto compute = [&](int buf, const bf16x8* B) {
#pragma unroll
    for (int s = 0; s < 4; ++s) {
      const char* lb = &lds[buf][0][0] + (s << 10) + lane * 16;
      bf16x8 a0 = *(const bf16x8*)(lb);
      bf16x8 a1 = *(const bf16x8*)(lb + 4096);
      bf16x8 a2 = *(const bf16x8*)(lb + 8192);
      bf16x8 a3 = *(const bf16x8*)(lb + 12288);
      acc0 = __builtin_amdgcn_mfma_f32_32x32x16_bf16(a0, B[s], acc0, 0, 0, 0);
      acc1 = __builtin_amdgcn_mfma_f32_32x32x16_bf16(a1, B[s], acc1, 0, 0, 0);
      acc2 = __builtin_amdgcn_mfma_f32_32x32x16_bf16(a2, B[s], acc2, 0, 0, 0);
      acc3 = __builtin_amdgcn_mfma_f32_32x32x16_bf16(a3, B[s], acc3, 0, 0, 0);
    }
  };

  bf16x8 BA[4], BB[4];

  // prologue: depth-3 gather prefetch + B(0)
  stage(0, 0); stage(1, 1); stage(2, 2);
  loadB(BA, 0);

  // steady: chunks 0..27 (unroll-2 for BA/BB ping-pong, no reg moves)
  for (int i = 0; i < 28; i += 2) {
    __builtin_amdgcn_s_barrier();                     // all done reading buf (i-1)&3
    stage((i + 3) & 3, i + 3);
    loadB(BB, i + 1);
    asm volatile("s_waitcnt vmcnt(8)" ::: "memory");  // stage(i) drained (own)
    __builtin_amdgcn_s_barrier();                     // everyone's stage(i) visible
    compute(i & 3, BA);

    __builtin_amdgcn_s_barrier();
    stage((i + 4) & 3, i + 4);
    loadB(BA, i + 2);
    asm volatile("s_waitcnt vmcnt(8)" ::: "memory");
    __builtin_amdgcn_s_barrier();
    compute((i + 1) & 3, BB);
  }
  // chunk 28 (last stage: 31)
  __builtin_amdgcn_s_barrier();
  stage(31 & 3, 31);
  loadB(BB, 29);
  asm volatile("s_waitcnt vmcnt(8)" ::: "memory");
  __builtin_amdgcn_s_barrier();
  compute(28 & 3, BA);
  // chunk 29 (stage(29): >=8 younger stage ops -> vmcnt(8) safe)
  __builtin_amdgcn_s_barrier();
  loadB(BA, 30);
  asm volatile("s_waitcnt vmcnt(8)" ::: "memory");
  __builtin_amdgcn_s_barrier();
  compute(29 & 3, BB);
  // chunk 30 (stage(30): only stage(31) younger -> vmcnt(4))
  __builtin_amdgcn_s_barrier();
  loadB(BB, 31);
  asm volatile("s_waitcnt vmcnt(4)" ::: "memory");
  __builtin_amdgcn_s_barrier();
  compute(30 & 3, BA);
  // chunk 31
  __builtin_amdgcn_s_barrier();
  asm volatile("s_waitcnt vmcnt(0)" ::: "memory");
  __builtin_amdgcn_s_barrier();
  compute(31 & 3, BB);

  // ---- distance ksteps 128,129: A rows all equal d[n][k-slice]
#pragma unroll
  for (int s = 0; s < 2; ++s) {
    bf16x8 bfr = *(const bf16x8*)(wfp + ((size_t)(128 + s) << 11));
    const char* dbase = (const char*)db + (size_t)n0 * 64 + s * 32 + half * 16;
    bf16x8 d0 = *(const bf16x8*)(dbase);
    bf16x8 d1 = *(const bf16x8*)(dbase + 64);
    bf16x8 d2 = *(const bf16x8*)(dbase + 128);
    bf16x8 d3 = *(const bf16x8*)(dbase + 192);
    acc0 = __builtin_amdgcn_mfma_f32_32x32x16_bf16(d0, bfr, acc0, 0, 0, 0);
    acc1 = __builtin_amdgcn_mfma_f32_32x32x16_bf16(d1, bfr, acc1, 0, 0, 0);
    acc2 = __builtin_amdgcn_mfma_f32_32x32x16_bf16(d2, bfr, acc2, 0, 0, 0);
    acc3 = __builtin_amdgcn_mfma_f32_32x32x16_bf16(d3, bfr, acc3, 0, 0, 0);
  }

  // ---- epilogue: D col=lane&31 -> out o, row=(r&3)+8*(r>>2)+4*half -> batch
  const int o = w * 32 + col;
  const float bv = bias[o];
#pragma unroll
  for (int r = 0; r < 16; ++r) {
    const int row = (r & 3) + 8 * (r >> 2) + 4 * half;
    float* op = out + ((size_t)row * NN + n0) * NOUT + o;
    op[0 * NOUT] = acc0[r] + bv;
    op[1 * NOUT] = acc1[r] + bv;
    op[2 * NOUT] = acc2[r] + bv;
    op[3 * NOUT] = acc3[r] + bv;
  }
}

// ---------------------------------------------------------------------------
extern "C" void kernel_launch(void* const* d_in, const int* in_sizes, int n_in,
                              void* d_out, int out_size, void* d_ws, size_t ws_size,
                              hipStream_t stream) {
  const float* x    = (const float*)d_in[0];
  const int*   nbrs = (const int*)d_in[1];
  const float* dist = (const float*)d_in[2];
  const float* W    = (const float*)d_in[3];
  const float* bias = (const float*)d_in[4];
  float* out = (float*)d_out;

  char* ws = (char*)d_ws;
  __bf16* xb2 = (__bf16*)(ws);                          // 2000*4096  = 8,192,000 B
  __bf16* Wf  = (__bf16*)(ws + 8192000);                // 130*256*16 =   532,480 B
  __bf16* db  = (__bf16*)(ws + 8192000 + 532480);       // 2000*32*2  =   128,000 B

  kprep<<<NN + NSTEP, 256, 0, stream>>>(x, dist, W, xb2, db, Wf);
  kmain<<<NN / 4, 256, 0, stream>>>(nbrs, bias, xb2, Wf, db, out);
}

// Round 4
// 54.198 us; speedup vs baseline: 1.1625x; 1.0195x over previous
//
#include <hip/hip_runtime.h>
#include <hip/hip_bf16.h>
#include <stdint.h>

typedef __attribute__((ext_vector_type(8)))  __bf16   bf16x8;
typedef __attribute__((ext_vector_type(16))) float    f32x16;
typedef __attribute__((ext_vector_type(8)))  float    f32x8;

#define NB   32
#define NN   2000
#define NK   32
#define NF   64
#define NOUT 128
#define NSTEP 130   // packed K: 2048 x-part + 32 dist, /16

#define GLOBAL_AS __attribute__((address_space(1)))
#define LDS_AS    __attribute__((address_space(3)))
#define SB() __builtin_amdgcn_sched_barrier(0)

// ---------------------------------------------------------------------------
// Fused prep. Blocks [0,NN): x -> xb2 frag-order tiles (+ dist -> db bf16).
//             Blocks [NN, NN+NSTEP): W -> Wf B-fragment order.
// xb2 tile byte t*16 holds x[batch=col][f=s*16+half*8+j], t=s*64+half*32+col.
// x-part threads ordered f-minor for coalesced 256B reads per batch row.
// ---------------------------------------------------------------------------
__global__ void kprep(const float* __restrict__ x, const float* __restrict__ dist,
                      const float* __restrict__ W,
                      __bf16* __restrict__ xb2, __bf16* __restrict__ db,
                      __bf16* __restrict__ Wf) {
  const int t = threadIdx.x;
  if (blockIdx.x < NN) {
    const int n = blockIdx.x;
    const int bb = t >> 3;          // batch 0..31
    const int f0 = (t & 7) << 3;    // feature start 0..56
    const float* src = x + ((size_t)bb * NN + n) * NF + f0;
    f32x8 v = *(const f32x8*)src;
    bf16x8 r;
#pragma unroll
    for (int j = 0; j < 8; ++j) r[j] = (__bf16)v[j];
    const int off = ((f0 >> 4) << 10) + (((f0 >> 3) & 1) << 9) + (bb << 4);
    *(bf16x8*)((char*)xb2 + ((size_t)n << 12) + off) = r;
    if (t < NK) db[n * NK + t] = (__bf16)dist[n * NK + t];
  } else {
    const int kstep = blockIdx.x - NN;                // 0..129
    const int lane = t & 63;
    const int wv = t >> 6;
    const int o = wv * 32 + (lane & 31);
    const int kbase = kstep * 16 + (lane >> 5) * 8;
    bf16x8 r;
#pragma unroll
    for (int j = 0; j < 8; ++j) {
      const int kg = kbase + j;
      const int c = (kg < 2048) ? ((kg >> 6) * 65 + (kg & 63)) : ((kg - 2048) * 65 + 64);
      r[j] = (__bf16)W[(size_t)o * 2080 + c];
    }
    *(bf16x8*)(Wf + (((size_t)kstep * 256 + t) << 3)) = r;
  }
}

// ---------------------------------------------------------------------------
// Main: block = 4 seq positions, 4 waves = 4 out-col groups (32 each).
// 4 LDS buffers (64KB), ONE barrier per chunk, issue order
// [loadB(j+1); stage(j+2)] + vmcnt(12): true depth-2 gather prefetch.
// 32 chunks (one neighbor slot each), 16 MFMA / chunk / wave.
// ---------------------------------------------------------------------------
__global__ __launch_bounds__(256, 2) void kmain(
    const int* __restrict__ nbrs, const float* __restrict__ bias,
    const __bf16* __restrict__ xb2, const __bf16* __restrict__ Wf,
    const __bf16* __restrict__ db, float* __restrict__ out) {
  __shared__ __align__(16) char lds[4][4][4096];   // [buf][n'][frag-order tile]

  const int n0   = blockIdx.x * 4;
  const int t    = threadIdx.x;
  const int lane = t & 63;
  const int w    = t >> 6;
  const int col  = lane & 31;
  const int half = lane >> 5;

  f32x16 acc0 = {}, acc1 = {}, acc2 = {}, acc3 = {};

  // lane c (c<32) holds this wave's n (= n0+w) neighbor index for slot c
  int myidx = 0;
  if (lane < NK) myidx = nbrs[(n0 + w) * NK + lane];

  const __bf16* wfp = Wf + (((size_t)(w * 64 + lane)) << 3);

  auto stage = [&](int buf, int c) {         // wave w stages tile of n0+w, nbr c
    const int nb = __builtin_amdgcn_readlane(myidx, c);
    const char* g = (const char*)xb2 + ((size_t)nb << 12) + lane * 16;
    char* l = &lds[buf][w][0];               // wave-uniform LDS base
#pragma unroll
    for (int q = 0; q < 4; ++q)
      __builtin_amdgcn_global_load_lds(
          (const GLOBAL_AS uint32_t*)(g + (q << 10)),
          (LDS_AS uint32_t*)(l + (q << 10)), 16, 0, 0);
  };

  auto loadB = [&](bf16x8* B, int i) {       // 4 B-frags for chunk i
#pragma unroll
    for (int s = 0; s < 4; ++s)
      B[s] = *(const bf16x8*)(wfp + ((size_t)(i * 4 + s) << 11));
  };

  auto compute = [&](int buf, const bf16x8* B) {
    __builtin_amdgcn_s_setprio(1);
#pragma unroll
    for (int s = 0; s < 4; ++s) {
      const char* lb = &lds[buf][0][0] + (s << 10) + lane * 16;
      bf16x8 a0 = *(const bf16x8*)(lb);
      bf16x8 a1 = *(const bf16x8*)(lb + 4096);
      bf16x8 a2 = *(const bf16x8*)(lb + 8192);
      bf16x8 a3 = *(const bf16x8*)(lb + 12288);
      acc0 = __builtin_amdgcn_mfma_f32_32x32x16_bf16(a0, B[s], acc0, 0, 0, 0);
      acc1 = __builtin_amdgcn_mfma_f32_32x32x16_bf16(a1, B[s], acc1, 0, 0, 0);
      acc2 = __builtin_amdgcn_mfma_f32_32x32x16_bf16(a2, B[s], acc2, 0, 0, 0);
      acc3 = __builtin_amdgcn_mfma_f32_32x32x16_bf16(a3, B[s], acc3, 0, 0, 0);
    }
    __builtin_amdgcn_s_setprio(0);
  };

  bf16x8 B0[4], B1[4];

  // prologue: issue order fixed so steady-state vmcnt(12) is uniform
  stage(0, 0); SB();
  loadB(B0, 0); SB();
  stage(1, 1); SB();

  // chunks 0..29 (even/odd pair per iteration; B0/B1 ping-pong)
  for (int j = 0; j < 30; j += 2) {
    // chunk j (even): compute with B0, prefetch B(j+1) into B1
    loadB(B1, j + 1); SB();
    stage((j + 2) & 3, j + 2); SB();
    asm volatile("s_waitcnt vmcnt(12)" ::: "memory");
    __builtin_amdgcn_s_barrier(); SB();
    compute(j & 3, B0);
    // chunk j+1 (odd): compute with B1, prefetch B(j+2) into B0
    loadB(B0, j + 2); SB();
    stage((j + 3) & 3, j + 3); SB();
    asm volatile("s_waitcnt vmcnt(12)" ::: "memory");
    __builtin_amdgcn_s_barrier(); SB();
    compute((j + 1) & 3, B1);
  }
  // chunk 30: last B prefetch; only stage(31)+loadB(31) younger than loadB(30)
  loadB(B1, 31); SB();
  asm volatile("s_waitcnt vmcnt(8)" ::: "memory");
  __builtin_amdgcn_s_barrier(); SB();
  compute(30 & 3, B0);
  // chunk 31
  asm volatile("s_waitcnt vmcnt(0)" ::: "memory");
  __builtin_amdgcn_s_barrier(); SB();
  compute(31 & 3, B1);

  // ---- distance ksteps 128,129: A rows all equal d[n][k-slice]
#pragma unroll
  for (int s = 0; s < 2; ++s) {
    bf16x8 bfr = *(const bf16x8*)(wfp + ((size_t)(128 + s) << 11));
    const char* dbase = (const char*)db + (size_t)n0 * 64 + s * 32 + half * 16;
    bf16x8 d0 = *(const bf16x8*)(dbase);
    bf16x8 d1 = *(const bf16x8*)(dbase + 64);
    bf16x8 d2 = *(const bf16x8*)(dbase + 128);
    bf16x8 d3 = *(const bf16x8*)(dbase + 192);
    acc0 = __builtin_amdgcn_mfma_f32_32x32x16_bf16(d0, bfr, acc0, 0, 0, 0);
    acc1 = __builtin_amdgcn_mfma_f32_32x32x16_bf16(d1, bfr, acc1, 0, 0, 0);
    acc2 = __builtin_amdgcn_mfma_f32_32x32x16_bf16(d2, bfr, acc2, 0, 0, 0);
    acc3 = __builtin_amdgcn_mfma_f32_32x32x16_bf16(d3, bfr, acc3, 0, 0, 0);
  }

  // ---- epilogue: D col=lane&31 -> out o, row=(r&3)+8*(r>>2)+4*half -> batch
  const int o = w * 32 + col;
  const float bv = bias[o];
#pragma unroll
  for (int r = 0; r < 16; ++r) {
    const int row = (r & 3) + 8 * (r >> 2) + 4 * half;
    float* op = out + ((size_t)row * NN + n0) * NOUT + o;
    op[0 * NOUT] = acc0[r] + bv;
    op[1 * NOUT] = acc1[r] + bv;
    op[2 * NOUT] = acc2[r] + bv;
    op[3 * NOUT] = acc3[r] + bv;
  }
}

// ---------------------------------------------------------------------------
extern "C" void kernel_launch(void* const* d_in, const int* in_sizes, int n_in,
                              void* d_out, int out_size, void* d_ws, size_t ws_size,
                              hipStream_t stream) {
  const float* x    = (const float*)d_in[0];
  const int*   nbrs = (const int*)d_in[1];
  const float* dist = (const float*)d_in[2];
  const float* W    = (const float*)d_in[3];
  const float* bias = (const float*)d_in[4];
  float* out = (float*)d_out;

  char* ws = (char*)d_ws;
  __bf16* xb2 = (__bf16*)(ws);                          // 2000*4096  = 8,192,000 B
  __bf16* Wf  = (__bf16*)(ws + 8192000);                // 130*256*16 =   532,480 B
  __bf16* db  = (__bf16*)(ws + 8192000 + 532480);       // 2000*32*2  =   128,000 B

  kprep<<<NN + NSTEP, 256, 0, stream>>>(x, dist, W, xb2, db, Wf);
  kmain<<<NN / 4, 256, 0, stream>>>(nbrs, bias, xb2, Wf, db, out);
}